// Round 1
// baseline (502.828 us; speedup 1.0000x reference)
//
#include <hip/hip_runtime.h>

// Reference reduces to a center crop:
//   data_out[b,c,i,j,k] = data[b,c,i+16,j+16,k+16]   (map_coordinates at exact
//   integer coords i+16.0 — fp32-exact, trilinear weights collapse to 1/0)
//   seg_out  = seg[:, :, 16:176, 16:176, 16:176]
// Shapes: in (4,2,192,192,192) f32, out 2x (4,2,160,160,160) f32 concat-flat.

constexpr unsigned P   = 160;           // patch edge
constexpr unsigned S   = 192;           // source edge
constexpr unsigned OFF = 16;            // crop offset
constexpr unsigned BC  = 8;             // 4*2 volumes per tensor
constexpr unsigned ROW4   = P / 4;                    // 40 float4 per out row
constexpr unsigned OUT4   = BC * P * P * ROW4;        // 8,192,000 float4 per tensor
constexpr unsigned TOTAL4 = 2 * OUT4;                 // 16,384,000 float4 total

__global__ __launch_bounds__(256) void crop_copy_kernel(
    const float4* __restrict__ data,
    const float4* __restrict__ seg,
    float4* __restrict__ out)
{
    unsigned idx = blockIdx.x * 256u + threadIdx.x;
    if (idx >= TOTAL4) return;

    const float4* src = data;
    float4* dst = out;
    unsigned o = idx;
    if (o >= OUT4) {            // second half of d_out = seg crop
        o -= OUT4;
        src = seg;
        dst = out + OUT4;
    }

    unsigned w4  = o % ROW4;          // float4 index within row
    unsigned row = o / ROW4;          // global out-row index
    unsigned h   = row % P;
    unsigned t   = row / P;
    unsigned d   = t % P;
    unsigned bc  = t / P;

    // input element offset of this row's first cropped element
    unsigned in_elem = bc * (S * S * S) + (d + OFF) * (S * S) + (h + OFF) * S + OFF;
    // in_elem is a multiple of 4 (192, 16 all mult. of 4) -> valid float4 index
    dst[o] = src[in_elem / 4 + w4];
}

extern "C" void kernel_launch(void* const* d_in, const int* in_sizes, int n_in,
                              void* d_out, int out_size, void* d_ws, size_t ws_size,
                              hipStream_t stream)
{
    const float4* data = (const float4*)d_in[0];
    const float4* seg  = (const float4*)d_in[1];
    float4* out = (float4*)d_out;

    constexpr unsigned block = 256;
    constexpr unsigned grid  = (TOTAL4 + block - 1) / block;   // 64,000 blocks
    crop_copy_kernel<<<grid, block, 0, stream>>>(data, seg, out);
}

// Round 2
// 486.206 us; speedup vs baseline: 1.0342x; 1.0342x over previous
//
#include <hip/hip_runtime.h>

// Reference reduces to a center crop (coords are fp32-exact integers i+16.0):
//   data_out[b,c,i,j,k] = data[b,c,i+16,j+16,k+16]
//   seg_out  = seg[:, :, 16:176, 16:176, 16:176]
// Shapes: in 2x (4,2,192,192,192) f32, out 2x (4,2,160,160,160) f32 concat-flat.
//
// Each thread handles ONE output offset o < OUT4 and copies BOTH tensors at
// that offset (same src index math, two independent loads/stores -> 2x MLP,
// half the integer div/mod work vs one-thread-per-float4).

constexpr unsigned P   = 160;           // patch edge
constexpr unsigned S   = 192;           // source edge
constexpr unsigned OFF = 16;            // crop offset
constexpr unsigned BC  = 8;             // 4*2 volumes per tensor
constexpr unsigned ROW4 = P / 4;                    // 40 float4 per out row
constexpr unsigned OUT4 = BC * P * P * ROW4;        // 8,192,000 float4 per tensor

using f4 = __attribute__((ext_vector_type(4))) float;

__global__ __launch_bounds__(256) void crop_copy_kernel(
    const f4* __restrict__ data,
    const f4* __restrict__ seg,
    f4* __restrict__ out)
{
    unsigned o = blockIdx.x * 256u + threadIdx.x;   // grid sized exactly: o < OUT4

    unsigned w4  = o % ROW4;          // float4 index within row
    unsigned row = o / ROW4;          // global out-row index
    unsigned h   = row % P;
    unsigned t   = row / P;
    unsigned d   = t % P;
    unsigned bc  = t / P;

    // input float4 index of this element (all terms multiples of 4 elements)
    unsigned src = (bc * (S * S * S) + (d + OFF) * (S * S) + (h + OFF) * S + OFF) / 4u + w4;

    f4 a = __builtin_nontemporal_load(&data[src]);
    f4 b = __builtin_nontemporal_load(&seg[src]);
    __builtin_nontemporal_store(a, &out[o]);
    __builtin_nontemporal_store(b, &out[o + OUT4]);
}

extern "C" void kernel_launch(void* const* d_in, const int* in_sizes, int n_in,
                              void* d_out, int out_size, void* d_ws, size_t ws_size,
                              hipStream_t stream)
{
    const f4* data = (const f4*)d_in[0];
    const f4* seg  = (const f4*)d_in[1];
    f4* out = (f4*)d_out;

    constexpr unsigned block = 256;
    constexpr unsigned grid  = OUT4 / block;   // 32,000 blocks, no tail
    crop_copy_kernel<<<grid, block, 0, stream>>>(data, seg, out);
}